// Round 9
// baseline (201.555 us; speedup 1.0000x reference)
//
#include <hip/hip_runtime.h>
#include <math.h>

#define H 64
#define HK 8
#define HD 64
#define DM 1024
#define WINDOW 128
#define GQA (H / HK)
#define Bv 2
#define Sv 1024

typedef _Float16 f16;
typedef __attribute__((ext_vector_type(8))) _Float16 f16x8;
typedef __attribute__((ext_vector_type(4))) _Float16 f16x4;
typedef __attribute__((ext_vector_type(4))) float f32x4;

__device__ __forceinline__ void gload_lds16(const void* g, void* l) {
    __builtin_amdgcn_global_load_lds((const __attribute__((address_space(1))) void*)g,
                                     (__attribute__((address_space(3))) void*)l, 16, 0, 0);
}

// ---------------------------------------------------------------------------
// QKV GEMM: 128x160 tile, BK=64, 256 thr = 4 waves (2x2, each 64x80 = 4x5
// MFMA 16x16x32). Grid 512 blocks = exactly 2/CU, single round.
// W = [Wq;Wk;Wv] fused [5120,1024] f16; epilogue routes per-16-col group:
//   cols [0,4096)    -> qh linear f16 (scaled by 1/8 for attention)
//   cols [4096,4608) -> khb[b][hk][s][d]
//   cols [4608,5120) -> vtb[b][hk][d][s]
// ---------------------------------------------------------------------------
__global__ __launch_bounds__(256, 2) void qkv_gemm(const f16* __restrict__ xh,
                                                   const f16* __restrict__ wqkv,
                                                   const float* __restrict__ bqkv,
                                                   f16* __restrict__ qh,
                                                   f16* __restrict__ khb,
                                                   f16* __restrict__ vtb) {
    __shared__ __align__(16) f16 As[128 * 64];
    __shared__ __align__(16) f16 Bs[160 * 64];

    const int t    = threadIdx.x;
    const int lane = t & 63;
    const int w    = t >> 6;
    const int lr   = lane & 15;
    const int quad = lane >> 4;
    const int srow = lane >> 3;
    const int gsw  = lane & 7;
    const int bx   = blockIdx.x & 31;
    const int by   = blockIdx.x >> 5;
    const int m0   = by * 128;
    const int n0   = bx * 160;
    const int wm   = w >> 1;
    const int wn   = w & 1;

    f32x4 acc[4][5] = {};

    for (int k0 = 0; k0 < DM; k0 += 64) {
#pragma unroll
        for (int i = 0; i < 4; ++i) {
            const int row = (w * 4 + i) * 8 + srow;
            const int g   = gsw ^ (row & 7);
            gload_lds16(xh + (size_t)(m0 + row) * DM + k0 + g * 8, As + (w * 4 + i) * 512);
        }
#pragma unroll
        for (int i = 0; i < 5; ++i) {
            const int row = (w * 5 + i) * 8 + srow;
            const int g   = gsw ^ (row & 7);
            gload_lds16(wqkv + (size_t)(n0 + row) * DM + k0 + g * 8, Bs + (w * 5 + i) * 512);
        }
        __syncthreads();
#pragma unroll
        for (int ks = 0; ks < 2; ++ks) {
            f16x8 af[4], bf[5];
#pragma unroll
            for (int tt = 0; tt < 4; ++tt) {
                const int m  = wm * 64 + tt * 16 + lr;
                const int ca = (ks * 4 + quad) ^ (m & 7);
                af[tt] = *(const f16x8*)(As + m * 64 + ca * 8);
            }
#pragma unroll
            for (int tt = 0; tt < 5; ++tt) {
                const int n  = wn * 80 + tt * 16 + lr;
                const int cb = (ks * 4 + quad) ^ (n & 7);
                bf[tt] = *(const f16x8*)(Bs + n * 64 + cb * 8);
            }
#pragma unroll
            for (int i = 0; i < 4; ++i)
#pragma unroll
                for (int j = 0; j < 5; ++j)
                    acc[i][j] = __builtin_amdgcn_mfma_f32_16x16x32_f16(af[i], bf[j], acc[i][j], 0, 0, 0);
        }
        __syncthreads();
    }

#pragma unroll
    for (int i = 0; i < 4; ++i) {
        const int grow = m0 + wm * 64 + i * 16 + quad * 4;
#pragma unroll
        for (int j = 0; j < 5; ++j) {
            const int gcb  = n0 + wn * 80 + j * 16;
            const int gcol = gcb + lr;
            const float bz = bqkv[gcol];
            if (gcb < 4096) {            // Q (pre-scaled by 1/8)
#pragma unroll
                for (int r = 0; r < 4; ++r)
                    qh[(size_t)(grow + r) * 4096 + gcol] = (f16)((acc[i][j][r] + bz) * 0.125f);
            } else if (gcb < 4608) {     // K: khb[((b*8+hk)*1024+s)*64+d]
                const int lc = gcol - 4096;
                const size_t base = (size_t)(grow >> 10) * 524288 + (size_t)(lc >> 6) * 65536
                                  + (size_t)(grow & 1023) * 64 + (lc & 63);
#pragma unroll
                for (int r = 0; r < 4; ++r)
                    khb[base + (size_t)r * 64] = (f16)(acc[i][j][r] + bz);
            } else {                     // V^T: vtb[((b*8+hk)*64+d)*1024+s]
                const int lc = gcol - 4608;
                const size_t base = ((size_t)(grow >> 10) * 512 + lc) * 1024 + (grow & 1023);
                f16x4 o;
#pragma unroll
                for (int r = 0; r < 4; ++r) o[r] = (f16)(acc[i][j][r] + bz);
                *(f16x4*)(vtb + base) = o;
            }
        }
    }
}

// ---------------------------------------------------------------------------
// O-projection split-K x4: 128x128 tile, fp32 partials (no bias).
// ---------------------------------------------------------------------------
__global__ __launch_bounds__(256, 2) void o_gemm_split(const f16* __restrict__ oh,
                                                       const f16* __restrict__ woh,
                                                       float* __restrict__ partials) {
    __shared__ __align__(16) f16 As[128 * 64];
    __shared__ __align__(16) f16 Bs[128 * 64];

    const int t    = threadIdx.x;
    const int lane = t & 63;
    const int w    = t >> 6;
    const int lr   = lane & 15;
    const int quad = lane >> 4;
    const int srow = lane >> 3;
    const int gsw  = lane & 7;
    const int kz   = blockIdx.z;
    const int m0   = blockIdx.y * 128;
    const int n0   = blockIdx.x * 128;
    const int wm   = w >> 1;
    const int wn   = w & 1;

    const f16* A = oh  + (size_t)kz * 1024;
    const f16* W = woh + (size_t)kz * 1024;
    float* P = partials + (size_t)kz * 2097152;

    f32x4 acc[4][4] = {};

    for (int k0 = 0; k0 < 1024; k0 += 64) {
#pragma unroll
        for (int i = 0; i < 4; ++i) {
            const int row = (w * 4 + i) * 8 + srow;
            const int g   = gsw ^ (row & 7);
            gload_lds16(A + (size_t)(m0 + row) * 4096 + k0 + g * 8, As + (w * 4 + i) * 512);
            gload_lds16(W + (size_t)(n0 + row) * 4096 + k0 + g * 8, Bs + (w * 4 + i) * 512);
        }
        __syncthreads();
#pragma unroll
        for (int ks = 0; ks < 2; ++ks) {
            f16x8 af[4], bf[4];
#pragma unroll
            for (int tt = 0; tt < 4; ++tt) {
                const int m  = wm * 64 + tt * 16 + lr;
                const int ca = (ks * 4 + quad) ^ (m & 7);
                af[tt] = *(const f16x8*)(As + m * 64 + ca * 8);
                const int n  = wn * 64 + tt * 16 + lr;
                const int cb = (ks * 4 + quad) ^ (n & 7);
                bf[tt] = *(const f16x8*)(Bs + n * 64 + cb * 8);
            }
#pragma unroll
            for (int i = 0; i < 4; ++i)
#pragma unroll
                for (int j = 0; j < 4; ++j)
                    acc[i][j] = __builtin_amdgcn_mfma_f32_16x16x32_f16(af[i], bf[j], acc[i][j], 0, 0, 0);
        }
        __syncthreads();
    }

#pragma unroll
    for (int i = 0; i < 4; ++i) {
        const int grow = m0 + wm * 64 + i * 16 + quad * 4;
#pragma unroll
        for (int j = 0; j < 4; ++j) {
            const int gcol = n0 + wn * 64 + j * 16 + lr;
#pragma unroll
            for (int r = 0; r < 4; ++r)
                P[(size_t)(grow + r) * 1024 + gcol] = acc[i][j][r];
        }
    }
}

__global__ __launch_bounds__(256) void reduce4(const float* __restrict__ partials,
                                               const float* __restrict__ bo,
                                               float* __restrict__ out) {
    const int i = blockIdx.x * 256 + threadIdx.x;
    const float4* p = (const float4*)partials;
    float4 a  = p[i];
    float4 b1 = p[i + 524288], b2 = p[i + 1048576], b3 = p[i + 1572864];
    float4 bz = ((const float4*)bo)[i & 255];
    float4 o;
    o.x = a.x + b1.x + b2.x + b3.x + bz.x;
    o.y = a.y + b1.y + b2.y + b3.y + bz.y;
    o.z = a.z + b1.z + b2.z + b3.z + bz.z;
    o.w = a.w + b1.w + b2.w + b3.w + bz.w;
    ((float4*)out)[i] = o;
}

// ---------------------------------------------------------------------------
// Fused fp32->f16 conversion + fused-bias build.
// ---------------------------------------------------------------------------
#define C_X  524288
#define C_WQ 1572864
#define C_WK 1703936
#define C_WV 1835008
#define C_WO 2883584

__global__ __launch_bounds__(256) void convert_all(const float* __restrict__ x,
                                                   const float* __restrict__ Wq,
                                                   const float* __restrict__ Wk,
                                                   const float* __restrict__ Wv,
                                                   const float* __restrict__ Wo,
                                                   const float* __restrict__ bq,
                                                   const float* __restrict__ bk,
                                                   const float* __restrict__ bv,
                                                   f16* __restrict__ xh,
                                                   f16* __restrict__ wqkv,
                                                   f16* __restrict__ woh,
                                                   float* __restrict__ bqkv) {
    const int i = blockIdx.x * 256 + threadIdx.x;
    if (i < 5120) {
        float v;
        if (i < 4096)      v = bq[i];
        else if (i < 4608) v = bk[i - 4096];
        else               v = bv[i - 4608];
        bqkv[i] = v;
    }
    const float* src;
    f16* dst;
    int off;
    if (i < C_X)       { src = x;  dst = xh;              off = i; }
    else if (i < C_WQ) { src = Wq; dst = wqkv;            off = i - C_X; }
    else if (i < C_WK) { src = Wk; dst = wqkv + 4194304;  off = i - C_WQ; }
    else if (i < C_WV) { src = Wv; dst = wqkv + 4718592;  off = i - C_WK; }
    else               { src = Wo; dst = woh;             off = i - C_WV; }
    const float4 v = ((const float4*)src)[off];
    f16x4 o;
    o[0] = (f16)v.x; o[1] = (f16)v.y; o[2] = (f16)v.z; o[3] = (f16)v.w;
    *(f16x4*)(dst + (size_t)off * 4) = o;
}

// ---------------------------------------------------------------------------
// MFMA flash attention v3. Block = 4 waves = 4 GQA heads of one (b,hk,q0).
// S^T = mfma(a=K, b=Q): C-layout [key=quad*4+r][q=lr] IS the B-operand
// layout of mfma_16x16x16f16 -> P feeds PV from registers (no P LDS).
// nt-outer loop: K/Vt LDS fragments read once (mt-invariant). Plain exp
// (no max-sub: |S| small by construction); l = per-lane partials + 2 shfls;
// sink adds exp(sk) to l. LDS 49.8 KB -> 3 blocks/CU.
// ---------------------------------------------------------------------------
#define VTS 200

__global__ __launch_bounds__(256, 3) void attn_mfma(const f16* __restrict__ qh,
                                                    const f16* __restrict__ khb,
                                                    const f16* __restrict__ vtb,
                                                    const float* __restrict__ sinks,
                                                    f16* __restrict__ oh) {
    __shared__ __align__(16) f16 Kl[192 * 64];
    __shared__ __align__(16) f16 Vt[64 * VTS];

    const int t  = threadIdx.x;
    const int q0 = blockIdx.x * 64;
    const int hk = blockIdx.y >> 1;
    const int hh = blockIdx.y & 1;
    const int b  = blockIdx.z;
    const int c0 = q0 - WINDOW;

    const int lane = t & 63;
    const int w    = t >> 6;
    const int lr   = lane & 15;
    const int quad = lane >> 4;
    const int srow = lane >> 3;
    const int gsw  = lane & 7;

    const f16* kg = khb + (size_t)(b * HK + hk) * Sv * HD;
    const f16* vg = vtb + (size_t)(b * HK + hk) * HD * Sv;

    // stage K: 192 rows x 64 f16, global_load_lds, xor swizzle on global chunk
#pragma unroll
    for (int it = 0; it < 6; ++it) {
        const int row = (w * 6 + it) * 8 + srow;      // 0..191
        const int g   = gsw ^ (row & 7);
        int j = c0 + row;
        if (j < 0) j = 0;                             // garbage -> masked
        gload_lds16(kg + (size_t)j * HD + g * 8, Kl + (w * 6 + it) * 512);
    }
    // stage V^T: 64 rows x 192 f16 (stride 200), manual 16B copies
#pragma unroll
    for (int it = 0; it < 6; ++it) {
        const int i = it * 256 + t;                   // 0..1535
        const int d = i / 24, c = i % 24;
        int j0 = c0 + c * 8;
        if (j0 < 0) j0 = 0;                           // garbage -> masked
        const f16x8 val = *(const f16x8*)(vg + (size_t)d * Sv + j0);
        *(f16x8*)(&Vt[d * VTS + c * 8]) = val;
    }
    __syncthreads();

    const int h = hk * GQA + hh * 4 + w;

    // Q fragments (B-operand): b[n=q-local=lr][k = ks*32 + quad*8 + jj]
    f16x8 qf[4][2];
#pragma unroll
    for (int mt = 0; mt < 4; ++mt) {
        const f16* qrow = qh + (size_t)(b * Sv + q0 + mt * 16 + lr) * 4096 + h * 64;
#pragma unroll
        for (int ks = 0; ks < 2; ++ks)
            qf[mt][ks] = *(const f16x8*)(qrow + ks * 32 + quad * 8);
    }
    const float sk   = sinks[h];
    const int   smin = (c0 < 0) ? -c0 : 0;

    f32x4 O[4][4] = {};          // O^T tiles [mt][dt]: row d=quad*4+r, col q=lr
    float lsum[4] = {0.f, 0.f, 0.f, 0.f};

#pragma unroll
    for (int nt = 0; nt < 12; ++nt) {
        // K fragments (A-operand): a[m=key-local=lr][k], xor-matched read
        f16x8 kf[2];
#pragma unroll
        for (int ks = 0; ks < 2; ++ks)
            kf[ks] = *(const f16x8*)(&Kl[(nt * 16 + lr) * 64 + (((ks * 4 + quad) ^ (lr & 7)) * 8)]);
        // V^T fragments (K=16 A-operand): a[m=d-local=lr][k=quad*4+jj]
        f16x4 vf[4];
#pragma unroll
        for (int dt = 0; dt < 4; ++dt)
            vf[dt] = *(const f16x4*)(&Vt[(dt * 16 + lr) * VTS + nt * 16 + quad * 4]);

#pragma unroll
        for (int mt = 0; mt < 4; ++mt) {
            if (nt < mt || nt > mt + 8) continue;     // tile fully masked
            // S^T tile: D[key][q]
            f32x4 S = {};
#pragma unroll
            for (int ks = 0; ks < 2; ++ks)
                S = __builtin_amdgcn_mfma_f32_16x16x32_f16(kf[ks], qf[mt][ks], S, 0, 0, 0);
            // mask + exp (no max-sub) + per-lane l partials + pack to f16
            f16x4 pf;
#pragma unroll
            for (int r = 0; r < 4; ++r) {
                const int sl = nt * 16 + quad * 4 + r;
                const int mq = mt * 16 + lr;
                const bool ok = (sl > mq) && (sl <= mq + WINDOW) && (sl >= smin);
                const float p = ok ? __expf(S[r]) : 0.f;
                lsum[mt] += p;
                pf[r] = (f16)p;
            }
            // O^T += V^T(16-slab) . P^T(16-slab)  [K=16 MFMA, P from regs]
#pragma unroll
            for (int dt = 0; dt < 4; ++dt)
                O[mt][dt] = __builtin_amdgcn_mfma_f32_16x16x16f16(vf[dt], pf, O[mt][dt], 0, 0, 0);
        }
    }

    // l: reduce per-lane partials across the 4 quads (same q=lr)
    const float esk = __expf(sk);
#pragma unroll
    for (int mt = 0; mt < 4; ++mt) {
        float l = lsum[mt];
        l += __shfl_xor(l, 16, 64);
        l += __shfl_xor(l, 32, 64);
        lsum[mt] = 1.f / (l + esk);        // sink column joins denominator
    }

    // epilogue: divide, pack f16x4 (d = quad*4+r contiguous), store 8B
#pragma unroll
    for (int mt = 0; mt < 4; ++mt) {
        const float inv = lsum[mt];
        f16* orow = oh + (size_t)(b * Sv + q0 + mt * 16 + lr) * 4096 + h * 64;
#pragma unroll
        for (int dt = 0; dt < 4; ++dt) {
            f16x4 ov;
#pragma unroll
            for (int r = 0; r < 4; ++r) ov[r] = (f16)(O[mt][dt][r] * inv);
            *(f16x4*)(orow + dt * 16 + quad * 4) = ov;
        }
    }
}

// ---------------------------------------------------------------------------
extern "C" void kernel_launch(void* const* d_in, const int* in_sizes, int n_in,
                              void* d_out, int out_size, void* d_ws, size_t ws_size,
                              hipStream_t stream) {
    const float* x     = (const float*)d_in[0];
    const float* Wq    = (const float*)d_in[1];
    const float* bq    = (const float*)d_in[2];
    const float* Wk    = (const float*)d_in[3];
    const float* bk    = (const float*)d_in[4];
    const float* Wv    = (const float*)d_in[5];
    const float* bv    = (const float*)d_in[6];
    const float* Wo    = (const float*)d_in[7];
    const float* bo    = (const float*)d_in[8];
    const float* sinks = (const float*)d_in[9];
    float* out = (float*)d_out;

    f16* xh   = (f16*)d_ws;                    // 2,097,152
    f16* wqkv = xh + 2097152;                  // 5,242,880
    f16* qh   = wqkv + 5242880;                // 8,388,608
    f16* khb  = qh + 8388608;                  // 1,048,576  [B][HK][S][HD]
    f16* vtb  = khb + 1048576;                 // 1,048,576  [B][HK][HD][S]
    f16* woh  = vtb + 1048576;                 // 4,194,304  LIVE at o_gemm
    f16* oh   = woh + 4194304;                 // 8,388,608  LIVE at o_gemm
    float* bqkv = (float*)(oh + 8388608);      // 5120 fp32
    float* partials = (float*)d_ws;            // 32 MB, aliases dead prefix

    convert_all<<<dim3(C_WO / 256), dim3(256), 0, stream>>>(
        x, Wq, Wk, Wv, Wo, bq, bk, bv, xh, wqkv, woh, bqkv);

    qkv_gemm<<<dim3(512), dim3(256), 0, stream>>>(xh, wqkv, bqkv, qh, khb, vtb);

    attn_mfma<<<dim3(Sv / 64, HK * 2, Bv), dim3(256), 0, stream>>>(qh, khb, vtb, sinks, oh);

    o_gemm_split<<<dim3(8, 16, 4), dim3(256), 0, stream>>>(oh, woh, partials);
    reduce4<<<dim3(2048), dim3(256), 0, stream>>>(partials, bo, out);
}

// Round 10
// 179.726 us; speedup vs baseline: 1.1215x; 1.1215x over previous
//
#include <hip/hip_runtime.h>
#include <math.h>

#define H 64
#define HK 8
#define HD 64
#define DM 1024
#define WINDOW 128
#define GQA (H / HK)
#define Bv 2
#define Sv 1024

typedef _Float16 f16;
typedef __attribute__((ext_vector_type(8))) _Float16 f16x8;
typedef __attribute__((ext_vector_type(4))) _Float16 f16x4;
typedef __attribute__((ext_vector_type(4))) float f32x4;

__device__ __forceinline__ void gload_lds16(const void* g, void* l) {
    __builtin_amdgcn_global_load_lds((const __attribute__((address_space(1))) void*)g,
                                     (__attribute__((address_space(3))) void*)l, 16, 0, 0);
}

// ---------------------------------------------------------------------------
// QKV GEMM: 128x160 tile, BK=64, 256 thr = 4 waves (2x2, each 64x80 = 4x5
// MFMA 16x16x32). Grid 512 blocks = exactly 2/CU, single round.
// W = [Wq;Wk;Wv] fused [5120,1024] f16; epilogue routes per-16-col group:
//   cols [0,4096)    -> qh linear f16 (scaled by 1/8 for attention)
//   cols [4096,4608) -> khb[b][hk][s][d]
//   cols [4608,5120) -> vtb[b][hk][d][s]
// ---------------------------------------------------------------------------
__global__ __launch_bounds__(256, 2) void qkv_gemm(const f16* __restrict__ xh,
                                                   const f16* __restrict__ wqkv,
                                                   const float* __restrict__ bqkv,
                                                   f16* __restrict__ qh,
                                                   f16* __restrict__ khb,
                                                   f16* __restrict__ vtb) {
    __shared__ __align__(16) f16 As[128 * 64];
    __shared__ __align__(16) f16 Bs[160 * 64];

    const int t    = threadIdx.x;
    const int lane = t & 63;
    const int w    = t >> 6;
    const int lr   = lane & 15;
    const int quad = lane >> 4;
    const int srow = lane >> 3;
    const int gsw  = lane & 7;
    const int bx   = blockIdx.x & 31;
    const int by   = blockIdx.x >> 5;
    const int m0   = by * 128;
    const int n0   = bx * 160;
    const int wm   = w >> 1;
    const int wn   = w & 1;

    f32x4 acc[4][5] = {};

    for (int k0 = 0; k0 < DM; k0 += 64) {
#pragma unroll
        for (int i = 0; i < 4; ++i) {
            const int row = (w * 4 + i) * 8 + srow;
            const int g   = gsw ^ (row & 7);
            gload_lds16(xh + (size_t)(m0 + row) * DM + k0 + g * 8, As + (w * 4 + i) * 512);
        }
#pragma unroll
        for (int i = 0; i < 5; ++i) {
            const int row = (w * 5 + i) * 8 + srow;
            const int g   = gsw ^ (row & 7);
            gload_lds16(wqkv + (size_t)(n0 + row) * DM + k0 + g * 8, Bs + (w * 5 + i) * 512);
        }
        __syncthreads();
#pragma unroll
        for (int ks = 0; ks < 2; ++ks) {
            f16x8 af[4], bf[5];
#pragma unroll
            for (int tt = 0; tt < 4; ++tt) {
                const int m  = wm * 64 + tt * 16 + lr;
                const int ca = (ks * 4 + quad) ^ (m & 7);
                af[tt] = *(const f16x8*)(As + m * 64 + ca * 8);
            }
#pragma unroll
            for (int tt = 0; tt < 5; ++tt) {
                const int n  = wn * 80 + tt * 16 + lr;
                const int cb = (ks * 4 + quad) ^ (n & 7);
                bf[tt] = *(const f16x8*)(Bs + n * 64 + cb * 8);
            }
#pragma unroll
            for (int i = 0; i < 4; ++i)
#pragma unroll
                for (int j = 0; j < 5; ++j)
                    acc[i][j] = __builtin_amdgcn_mfma_f32_16x16x32_f16(af[i], bf[j], acc[i][j], 0, 0, 0);
        }
        __syncthreads();
    }

#pragma unroll
    for (int i = 0; i < 4; ++i) {
        const int grow = m0 + wm * 64 + i * 16 + quad * 4;
#pragma unroll
        for (int j = 0; j < 5; ++j) {
            const int gcb  = n0 + wn * 80 + j * 16;
            const int gcol = gcb + lr;
            const float bz = bqkv[gcol];
            if (gcb < 4096) {            // Q (pre-scaled by 1/8)
#pragma unroll
                for (int r = 0; r < 4; ++r)
                    qh[(size_t)(grow + r) * 4096 + gcol] = (f16)((acc[i][j][r] + bz) * 0.125f);
            } else if (gcb < 4608) {     // K: khb[((b*8+hk)*1024+s)*64+d]
                const int lc = gcol - 4096;
                const size_t base = (size_t)(grow >> 10) * 524288 + (size_t)(lc >> 6) * 65536
                                  + (size_t)(grow & 1023) * 64 + (lc & 63);
#pragma unroll
                for (int r = 0; r < 4; ++r)
                    khb[base + (size_t)r * 64] = (f16)(acc[i][j][r] + bz);
            } else {                     // V^T: vtb[((b*8+hk)*64+d)*1024+s]
                const int lc = gcol - 4608;
                const size_t base = ((size_t)(grow >> 10) * 512 + lc) * 1024 + (grow & 1023);
                f16x4 o;
#pragma unroll
                for (int r = 0; r < 4; ++r) o[r] = (f16)(acc[i][j][r] + bz);
                *(f16x4*)(vtb + base) = o;
            }
        }
    }
}

// ---------------------------------------------------------------------------
// O-projection split-K x4: 128x128 tile, fp32 partials (no bias).
// ---------------------------------------------------------------------------
__global__ __launch_bounds__(256, 2) void o_gemm_split(const f16* __restrict__ oh,
                                                       const f16* __restrict__ woh,
                                                       float* __restrict__ partials) {
    __shared__ __align__(16) f16 As[128 * 64];
    __shared__ __align__(16) f16 Bs[128 * 64];

    const int t    = threadIdx.x;
    const int lane = t & 63;
    const int w    = t >> 6;
    const int lr   = lane & 15;
    const int quad = lane >> 4;
    const int srow = lane >> 3;
    const int gsw  = lane & 7;
    const int kz   = blockIdx.z;
    const int m0   = blockIdx.y * 128;
    const int n0   = blockIdx.x * 128;
    const int wm   = w >> 1;
    const int wn   = w & 1;

    const f16* A = oh  + (size_t)kz * 1024;
    const f16* W = woh + (size_t)kz * 1024;
    float* P = partials + (size_t)kz * 2097152;

    f32x4 acc[4][4] = {};

    for (int k0 = 0; k0 < 1024; k0 += 64) {
#pragma unroll
        for (int i = 0; i < 4; ++i) {
            const int row = (w * 4 + i) * 8 + srow;
            const int g   = gsw ^ (row & 7);
            gload_lds16(A + (size_t)(m0 + row) * 4096 + k0 + g * 8, As + (w * 4 + i) * 512);
            gload_lds16(W + (size_t)(n0 + row) * 4096 + k0 + g * 8, Bs + (w * 4 + i) * 512);
        }
        __syncthreads();
#pragma unroll
        for (int ks = 0; ks < 2; ++ks) {
            f16x8 af[4], bf[4];
#pragma unroll
            for (int tt = 0; tt < 4; ++tt) {
                const int m  = wm * 64 + tt * 16 + lr;
                const int ca = (ks * 4 + quad) ^ (m & 7);
                af[tt] = *(const f16x8*)(As + m * 64 + ca * 8);
                const int n  = wn * 64 + tt * 16 + lr;
                const int cb = (ks * 4 + quad) ^ (n & 7);
                bf[tt] = *(const f16x8*)(Bs + n * 64 + cb * 8);
            }
#pragma unroll
            for (int i = 0; i < 4; ++i)
#pragma unroll
                for (int j = 0; j < 4; ++j)
                    acc[i][j] = __builtin_amdgcn_mfma_f32_16x16x32_f16(af[i], bf[j], acc[i][j], 0, 0, 0);
        }
        __syncthreads();
    }

#pragma unroll
    for (int i = 0; i < 4; ++i) {
        const int grow = m0 + wm * 64 + i * 16 + quad * 4;
#pragma unroll
        for (int j = 0; j < 4; ++j) {
            const int gcol = n0 + wn * 64 + j * 16 + lr;
#pragma unroll
            for (int r = 0; r < 4; ++r)
                P[(size_t)(grow + r) * 1024 + gcol] = acc[i][j][r];
        }
    }
}

__global__ __launch_bounds__(256) void reduce4(const float* __restrict__ partials,
                                               const float* __restrict__ bo,
                                               float* __restrict__ out) {
    const int i = blockIdx.x * 256 + threadIdx.x;
    const float4* p = (const float4*)partials;
    float4 a  = p[i];
    float4 b1 = p[i + 524288], b2 = p[i + 1048576], b3 = p[i + 1572864];
    float4 bz = ((const float4*)bo)[i & 255];
    float4 o;
    o.x = a.x + b1.x + b2.x + b3.x + bz.x;
    o.y = a.y + b1.y + b2.y + b3.y + bz.y;
    o.z = a.z + b1.z + b2.z + b3.z + bz.z;
    o.w = a.w + b1.w + b2.w + b3.w + bz.w;
    ((float4*)out)[i] = o;
}

// ---------------------------------------------------------------------------
// Fused fp32->f16 conversion + fused-bias build.
// ---------------------------------------------------------------------------
#define C_X  524288
#define C_WQ 1572864
#define C_WK 1703936
#define C_WV 1835008
#define C_WO 2883584

__global__ __launch_bounds__(256) void convert_all(const float* __restrict__ x,
                                                   const float* __restrict__ Wq,
                                                   const float* __restrict__ Wk,
                                                   const float* __restrict__ Wv,
                                                   const float* __restrict__ Wo,
                                                   const float* __restrict__ bq,
                                                   const float* __restrict__ bk,
                                                   const float* __restrict__ bv,
                                                   f16* __restrict__ xh,
                                                   f16* __restrict__ wqkv,
                                                   f16* __restrict__ woh,
                                                   float* __restrict__ bqkv) {
    const int i = blockIdx.x * 256 + threadIdx.x;
    if (i < 5120) {
        float v;
        if (i < 4096)      v = bq[i];
        else if (i < 4608) v = bk[i - 4096];
        else               v = bv[i - 4608];
        bqkv[i] = v;
    }
    const float* src;
    f16* dst;
    int off;
    if (i < C_X)       { src = x;  dst = xh;              off = i; }
    else if (i < C_WQ) { src = Wq; dst = wqkv;            off = i - C_X; }
    else if (i < C_WK) { src = Wk; dst = wqkv + 4194304;  off = i - C_WQ; }
    else if (i < C_WV) { src = Wv; dst = wqkv + 4718592;  off = i - C_WK; }
    else               { src = Wo; dst = woh;             off = i - C_WV; }
    const float4 v = ((const float4*)src)[off];
    f16x4 o;
    o[0] = (f16)v.x; o[1] = (f16)v.y; o[2] = (f16)v.z; o[3] = (f16)v.w;
    *(f16x4*)(dst + (size_t)off * 4) = o;
}

// ---------------------------------------------------------------------------
// MFMA flash attention v3. Block = 4 waves = 4 GQA heads of one (b,hk,q0).
// S^T = mfma(a=K, b=Q): C-layout [key=quad*4+r][q=lr] IS the B-operand
// layout of mfma_16x16x16f16 -> P feeds PV from registers (no P LDS).
// nt-outer loop: K/Vt LDS fragments read once (mt-invariant). Plain exp
// (no max-sub: |S| small by construction); l = per-lane partials + 2 shfls;
// sink adds exp(sk) to l. LDS 49.8 KB.
// launch_bounds(256,2): R9's (256,3) capped VGPRs below the ~150 needed
// (O 64 + qf 32 + kf/vf 16 + temps) -> scratch spill, 70 MB HBM writes.
// ---------------------------------------------------------------------------
#define VTS 200

__global__ __launch_bounds__(256, 2) void attn_mfma(const f16* __restrict__ qh,
                                                    const f16* __restrict__ khb,
                                                    const f16* __restrict__ vtb,
                                                    const float* __restrict__ sinks,
                                                    f16* __restrict__ oh) {
    __shared__ __align__(16) f16 Kl[192 * 64];
    __shared__ __align__(16) f16 Vt[64 * VTS];

    const int t  = threadIdx.x;
    const int q0 = blockIdx.x * 64;
    const int hk = blockIdx.y >> 1;
    const int hh = blockIdx.y & 1;
    const int b  = blockIdx.z;
    const int c0 = q0 - WINDOW;

    const int lane = t & 63;
    const int w    = t >> 6;
    const int lr   = lane & 15;
    const int quad = lane >> 4;
    const int srow = lane >> 3;
    const int gsw  = lane & 7;

    const f16* kg = khb + (size_t)(b * HK + hk) * Sv * HD;
    const f16* vg = vtb + (size_t)(b * HK + hk) * HD * Sv;

    // stage K: 192 rows x 64 f16, global_load_lds, xor swizzle on global chunk
#pragma unroll
    for (int it = 0; it < 6; ++it) {
        const int row = (w * 6 + it) * 8 + srow;      // 0..191
        const int g   = gsw ^ (row & 7);
        int j = c0 + row;
        if (j < 0) j = 0;                             // garbage -> masked
        gload_lds16(kg + (size_t)j * HD + g * 8, Kl + (w * 6 + it) * 512);
    }
    // stage V^T: 64 rows x 192 f16 (stride 200), manual 16B copies
#pragma unroll
    for (int it = 0; it < 6; ++it) {
        const int i = it * 256 + t;                   // 0..1535
        const int d = i / 24, c = i % 24;
        int j0 = c0 + c * 8;
        if (j0 < 0) j0 = 0;                           // garbage -> masked
        const f16x8 val = *(const f16x8*)(vg + (size_t)d * Sv + j0);
        *(f16x8*)(&Vt[d * VTS + c * 8]) = val;
    }
    __syncthreads();

    const int h = hk * GQA + hh * 4 + w;

    // Q fragments (B-operand): b[n=q-local=lr][k = ks*32 + quad*8 + jj]
    f16x8 qf[4][2];
#pragma unroll
    for (int mt = 0; mt < 4; ++mt) {
        const f16* qrow = qh + (size_t)(b * Sv + q0 + mt * 16 + lr) * 4096 + h * 64;
#pragma unroll
        for (int ks = 0; ks < 2; ++ks)
            qf[mt][ks] = *(const f16x8*)(qrow + ks * 32 + quad * 8);
    }
    const float sk   = sinks[h];
    const int   smin = (c0 < 0) ? -c0 : 0;

    f32x4 O[4][4] = {};          // O^T tiles [mt][dt]: row d=quad*4+r, col q=lr
    float lsum[4] = {0.f, 0.f, 0.f, 0.f};

#pragma unroll
    for (int nt = 0; nt < 12; ++nt) {
        // K fragments (A-operand): a[m=key-local=lr][k], xor-matched read
        f16x8 kf[2];
#pragma unroll
        for (int ks = 0; ks < 2; ++ks)
            kf[ks] = *(const f16x8*)(&Kl[(nt * 16 + lr) * 64 + (((ks * 4 + quad) ^ (lr & 7)) * 8)]);
        // V^T fragments (K=16 A-operand): a[m=d-local=lr][k=quad*4+jj]
        f16x4 vf[4];
#pragma unroll
        for (int dt = 0; dt < 4; ++dt)
            vf[dt] = *(const f16x4*)(&Vt[(dt * 16 + lr) * VTS + nt * 16 + quad * 4]);

#pragma unroll
        for (int mt = 0; mt < 4; ++mt) {
            if (nt < mt || nt > mt + 8) continue;     // tile fully masked
            // S^T tile: D[key][q]
            f32x4 S = {};
#pragma unroll
            for (int ks = 0; ks < 2; ++ks)
                S = __builtin_amdgcn_mfma_f32_16x16x32_f16(kf[ks], qf[mt][ks], S, 0, 0, 0);
            // mask + exp (no max-sub) + per-lane l partials + pack to f16
            f16x4 pf;
#pragma unroll
            for (int r = 0; r < 4; ++r) {
                const int sl = nt * 16 + quad * 4 + r;
                const int mq = mt * 16 + lr;
                const bool ok = (sl > mq) && (sl <= mq + WINDOW) && (sl >= smin);
                const float p = ok ? __expf(S[r]) : 0.f;
                lsum[mt] += p;
                pf[r] = (f16)p;
            }
            // O^T += V^T(16-slab) . P^T(16-slab)  [K=16 MFMA, P from regs]
#pragma unroll
            for (int dt = 0; dt < 4; ++dt)
                O[mt][dt] = __builtin_amdgcn_mfma_f32_16x16x16f16(vf[dt], pf, O[mt][dt], 0, 0, 0);
        }
    }

    // l: reduce per-lane partials across the 4 quads (same q=lr)
    const float esk = __expf(sk);
#pragma unroll
    for (int mt = 0; mt < 4; ++mt) {
        float l = lsum[mt];
        l += __shfl_xor(l, 16, 64);
        l += __shfl_xor(l, 32, 64);
        lsum[mt] = 1.f / (l + esk);        // sink column joins denominator
    }

    // epilogue: divide, pack f16x4 (d = quad*4+r contiguous), store 8B
#pragma unroll
    for (int mt = 0; mt < 4; ++mt) {
        const float inv = lsum[mt];
        f16* orow = oh + (size_t)(b * Sv + q0 + mt * 16 + lr) * 4096 + h * 64;
#pragma unroll
        for (int dt = 0; dt < 4; ++dt) {
            f16x4 ov;
#pragma unroll
            for (int r = 0; r < 4; ++r) ov[r] = (f16)(O[mt][dt][r] * inv);
            *(f16x4*)(orow + dt * 16 + quad * 4) = ov;
        }
    }
}

// ---------------------------------------------------------------------------
extern "C" void kernel_launch(void* const* d_in, const int* in_sizes, int n_in,
                              void* d_out, int out_size, void* d_ws, size_t ws_size,
                              hipStream_t stream) {
    const float* x     = (const float*)d_in[0];
    const float* Wq    = (const float*)d_in[1];
    const float* bq    = (const float*)d_in[2];
    const float* Wk    = (const float*)d_in[3];
    const float* bk    = (const float*)d_in[4];
    const float* Wv    = (const float*)d_in[5];
    const float* bv    = (const float*)d_in[6];
    const float* Wo    = (const float*)d_in[7];
    const float* bo    = (const float*)d_in[8];
    const float* sinks = (const float*)d_in[9];
    float* out = (float*)d_out;

    f16* xh   = (f16*)d_ws;                    // 2,097,152
    f16* wqkv = xh + 2097152;                  // 5,242,880
    f16* qh   = wqkv + 5242880;                // 8,388,608
    f16* khb  = qh + 8388608;                  // 1,048,576  [B][HK][S][HD]
    f16* vtb  = khb + 1048576;                 // 1,048,576  [B][HK][HD][S]
    f16* woh  = vtb + 1048576;                 // 4,194,304  LIVE at o_gemm
    f16* oh   = woh + 4194304;                 // 8,388,608  LIVE at o_gemm
    float* bqkv = (float*)(oh + 8388608);      // 5120 fp32
    float* partials = (float*)d_ws;            // 32 MB, aliases dead prefix

    convert_all<<<dim3(C_WO / 256), dim3(256), 0, stream>>>(
        x, Wq, Wk, Wv, Wo, bq, bk, bv, xh, wqkv, woh, bqkv);

    qkv_gemm<<<dim3(512), dim3(256), 0, stream>>>(xh, wqkv, bqkv, qh, khb, vtb);

    attn_mfma<<<dim3(Sv / 64, HK * 2, Bv), dim3(256), 0, stream>>>(qh, khb, vtb, sinks, oh);

    o_gemm_split<<<dim3(8, 16, 4), dim3(256), 0, stream>>>(oh, woh, partials);
    reduce4<<<dim3(2048), dim3(256), 0, stream>>>(partials, bo, out);
}

// Round 11
// 175.032 us; speedup vs baseline: 1.1515x; 1.0268x over previous
//
#include <hip/hip_runtime.h>
#include <math.h>

#define H 64
#define HK 8
#define HD 64
#define DM 1024
#define WINDOW 128
#define GQA (H / HK)
#define Bv 2
#define Sv 1024

typedef _Float16 f16;
typedef __attribute__((ext_vector_type(8))) _Float16 f16x8;
typedef __attribute__((ext_vector_type(4))) _Float16 f16x4;
typedef __attribute__((ext_vector_type(4))) float f32x4;

__device__ __forceinline__ void gload_lds16(const void* g, void* l) {
    __builtin_amdgcn_global_load_lds((const __attribute__((address_space(1))) void*)g,
                                     (__attribute__((address_space(3))) void*)l, 16, 0, 0);
}

// ---------------------------------------------------------------------------
// QKV GEMM: 128x160 tile, BK=64, 256 thr = 4 waves (2x2, each 64x80 = 4x5
// MFMA 16x16x32). Grid 512 blocks = exactly 2/CU.
// XCD-aware supertile swizzle: blocks round-robin to XCDs by blockIdx%8.
// Supertile = 8bx x 8by = 64 consecutive ids; within it, XCD x gets
// bx_local = x (fixed), by_local = 0..7 -> per-XCD L2 working set =
// one B-tile (0.32 MB) + 8 A-row-tiles (2 MB) = 2.3 MB < 4 MB L2.
// Without this, footprint was 5.3 MB -> L2 thrash -> 296 MB from L3 (the
// measured 44 us = 6.7 TB/s L3 ceiling).
// ---------------------------------------------------------------------------
__global__ __launch_bounds__(256, 2) void qkv_gemm(const f16* __restrict__ xh,
                                                   const f16* __restrict__ wqkv,
                                                   const float* __restrict__ bqkv,
                                                   f16* __restrict__ qh,
                                                   f16* __restrict__ khb,
                                                   f16* __restrict__ vtb) {
    __shared__ __align__(16) f16 As[128 * 64];
    __shared__ __align__(16) f16 Bs[160 * 64];

    const int t    = threadIdx.x;
    const int lane = t & 63;
    const int w    = t >> 6;
    const int lr   = lane & 15;
    const int quad = lane >> 4;
    const int srow = lane >> 3;
    const int gsw  = lane & 7;

    // supertile swizzle: id -> (bx, by)
    const int id    = blockIdx.x;
    const int s     = id >> 6;          // supertile 0..7 (4 bx-groups x 2 by-groups)
    const int local = id & 63;
    const int bx    = (s & 3) * 8 + (local & 7);   // local%8 == XCD slot
    const int by    = (s >> 2) * 8 + (local >> 3);

    const int m0   = by * 128;
    const int n0   = bx * 160;
    const int wm   = w >> 1;
    const int wn   = w & 1;

    f32x4 acc[4][5] = {};

    for (int k0 = 0; k0 < DM; k0 += 64) {
#pragma unroll
        for (int i = 0; i < 4; ++i) {
            const int row = (w * 4 + i) * 8 + srow;
            const int g   = gsw ^ (row & 7);
            gload_lds16(xh + (size_t)(m0 + row) * DM + k0 + g * 8, As + (w * 4 + i) * 512);
        }
#pragma unroll
        for (int i = 0; i < 5; ++i) {
            const int row = (w * 5 + i) * 8 + srow;
            const int g   = gsw ^ (row & 7);
            gload_lds16(wqkv + (size_t)(n0 + row) * DM + k0 + g * 8, Bs + (w * 5 + i) * 512);
        }
        __syncthreads();
#pragma unroll
        for (int ks = 0; ks < 2; ++ks) {
            f16x8 af[4], bf[5];
#pragma unroll
            for (int tt = 0; tt < 4; ++tt) {
                const int m  = wm * 64 + tt * 16 + lr;
                const int ca = (ks * 4 + quad) ^ (m & 7);
                af[tt] = *(const f16x8*)(As + m * 64 + ca * 8);
            }
#pragma unroll
            for (int tt = 0; tt < 5; ++tt) {
                const int n  = wn * 80 + tt * 16 + lr;
                const int cb = (ks * 4 + quad) ^ (n & 7);
                bf[tt] = *(const f16x8*)(Bs + n * 64 + cb * 8);
            }
#pragma unroll
            for (int i = 0; i < 4; ++i)
#pragma unroll
                for (int j = 0; j < 5; ++j)
                    acc[i][j] = __builtin_amdgcn_mfma_f32_16x16x32_f16(af[i], bf[j], acc[i][j], 0, 0, 0);
        }
        __syncthreads();
    }

#pragma unroll
    for (int i = 0; i < 4; ++i) {
        const int grow = m0 + wm * 64 + i * 16 + quad * 4;
#pragma unroll
        for (int j = 0; j < 5; ++j) {
            const int gcb  = n0 + wn * 80 + j * 16;
            const int gcol = gcb + lr;
            const float bz = bqkv[gcol];
            if (gcb < 4096) {            // Q (pre-scaled by 1/8)
#pragma unroll
                for (int r = 0; r < 4; ++r)
                    qh[(size_t)(grow + r) * 4096 + gcol] = (f16)((acc[i][j][r] + bz) * 0.125f);
            } else if (gcb < 4608) {     // K: khb[((b*8+hk)*1024+s)*64+d]
                const int lc = gcol - 4096;
                const size_t base = (size_t)(grow >> 10) * 524288 + (size_t)(lc >> 6) * 65536
                                  + (size_t)(grow & 1023) * 64 + (lc & 63);
#pragma unroll
                for (int r = 0; r < 4; ++r)
                    khb[base + (size_t)r * 64] = (f16)(acc[i][j][r] + bz);
            } else {                     // V^T: vtb[((b*8+hk)*64+d)*1024+s]
                const int lc = gcol - 4608;
                const size_t base = ((size_t)(grow >> 10) * 512 + lc) * 1024 + (grow & 1023);
                f16x4 o;
#pragma unroll
                for (int r = 0; r < 4; ++r) o[r] = (f16)(acc[i][j][r] + bz);
                *(f16x4*)(vtb + base) = o;
            }
        }
    }
}

// ---------------------------------------------------------------------------
// O-projection split-K x4: 128x128 tile, fp32 partials (no bias).
// 1D grid 512 with supertile swizzle: per kz, supertile = 8bx x 8by;
// XCD x gets by_local = x (A-tile 0.25 MB) + all 8 bx (W-slice 2 MB)
// -> 2.25 MB per-XCD L2 working set.
// ---------------------------------------------------------------------------
__global__ __launch_bounds__(256, 2) void o_gemm_split(const f16* __restrict__ oh,
                                                       const f16* __restrict__ woh,
                                                       float* __restrict__ partials) {
    __shared__ __align__(16) f16 As[128 * 64];
    __shared__ __align__(16) f16 Bs[128 * 64];

    const int t    = threadIdx.x;
    const int lane = t & 63;
    const int w    = t >> 6;
    const int lr   = lane & 15;
    const int quad = lane >> 4;
    const int srow = lane >> 3;
    const int gsw  = lane & 7;

    // supertile swizzle: id -> (kz, bx, by)
    const int id    = blockIdx.x;
    const int kz    = id >> 7;
    const int r_    = id & 127;
    const int st    = r_ >> 6;          // by-group 0/1
    const int local = r_ & 63;
    const int by    = st * 8 + (local & 7);   // local%8 == XCD slot
    const int bx    = local >> 3;

    const int m0   = by * 128;
    const int n0   = bx * 128;
    const int wm   = w >> 1;
    const int wn   = w & 1;

    const f16* A = oh  + (size_t)kz * 1024;
    const f16* W = woh + (size_t)kz * 1024;
    float* P = partials + (size_t)kz * 2097152;

    f32x4 acc[4][4] = {};

    for (int k0 = 0; k0 < 1024; k0 += 64) {
#pragma unroll
        for (int i = 0; i < 4; ++i) {
            const int row = (w * 4 + i) * 8 + srow;
            const int g   = gsw ^ (row & 7);
            gload_lds16(A + (size_t)(m0 + row) * 4096 + k0 + g * 8, As + (w * 4 + i) * 512);
            gload_lds16(W + (size_t)(n0 + row) * 4096 + k0 + g * 8, Bs + (w * 4 + i) * 512);
        }
        __syncthreads();
#pragma unroll
        for (int ks = 0; ks < 2; ++ks) {
            f16x8 af[4], bf[4];
#pragma unroll
            for (int tt = 0; tt < 4; ++tt) {
                const int m  = wm * 64 + tt * 16 + lr;
                const int ca = (ks * 4 + quad) ^ (m & 7);
                af[tt] = *(const f16x8*)(As + m * 64 + ca * 8);
                const int n  = wn * 64 + tt * 16 + lr;
                const int cb = (ks * 4 + quad) ^ (n & 7);
                bf[tt] = *(const f16x8*)(Bs + n * 64 + cb * 8);
            }
#pragma unroll
            for (int i = 0; i < 4; ++i)
#pragma unroll
                for (int j = 0; j < 4; ++j)
                    acc[i][j] = __builtin_amdgcn_mfma_f32_16x16x32_f16(af[i], bf[j], acc[i][j], 0, 0, 0);
        }
        __syncthreads();
    }

#pragma unroll
    for (int i = 0; i < 4; ++i) {
        const int grow = m0 + wm * 64 + i * 16 + quad * 4;
#pragma unroll
        for (int j = 0; j < 4; ++j) {
            const int gcol = n0 + wn * 64 + j * 16 + lr;
#pragma unroll
            for (int r = 0; r < 4; ++r)
                P[(size_t)(grow + r) * 1024 + gcol] = acc[i][j][r];
        }
    }
}

__global__ __launch_bounds__(256) void reduce4(const float* __restrict__ partials,
                                               const float* __restrict__ bo,
                                               float* __restrict__ out) {
    const int i = blockIdx.x * 256 + threadIdx.x;
    const float4* p = (const float4*)partials;
    float4 a  = p[i];
    float4 b1 = p[i + 524288], b2 = p[i + 1048576], b3 = p[i + 1572864];
    float4 bz = ((const float4*)bo)[i & 255];
    float4 o;
    o.x = a.x + b1.x + b2.x + b3.x + bz.x;
    o.y = a.y + b1.y + b2.y + b3.y + bz.y;
    o.z = a.z + b1.z + b2.z + b3.z + bz.z;
    o.w = a.w + b1.w + b2.w + b3.w + bz.w;
    ((float4*)out)[i] = o;
}

// ---------------------------------------------------------------------------
// Fused fp32->f16 conversion + fused-bias build.
// ---------------------------------------------------------------------------
#define C_X  524288
#define C_WQ 1572864
#define C_WK 1703936
#define C_WV 1835008
#define C_WO 2883584

__global__ __launch_bounds__(256) void convert_all(const float* __restrict__ x,
                                                   const float* __restrict__ Wq,
                                                   const float* __restrict__ Wk,
                                                   const float* __restrict__ Wv,
                                                   const float* __restrict__ Wo,
                                                   const float* __restrict__ bq,
                                                   const float* __restrict__ bk,
                                                   const float* __restrict__ bv,
                                                   f16* __restrict__ xh,
                                                   f16* __restrict__ wqkv,
                                                   f16* __restrict__ woh,
                                                   float* __restrict__ bqkv) {
    const int i = blockIdx.x * 256 + threadIdx.x;
    if (i < 5120) {
        float v;
        if (i < 4096)      v = bq[i];
        else if (i < 4608) v = bk[i - 4096];
        else               v = bv[i - 4608];
        bqkv[i] = v;
    }
    const float* src;
    f16* dst;
    int off;
    if (i < C_X)       { src = x;  dst = xh;              off = i; }
    else if (i < C_WQ) { src = Wq; dst = wqkv;            off = i - C_X; }
    else if (i < C_WK) { src = Wk; dst = wqkv + 4194304;  off = i - C_WQ; }
    else if (i < C_WV) { src = Wv; dst = wqkv + 4718592;  off = i - C_WK; }
    else               { src = Wo; dst = woh;             off = i - C_WV; }
    const float4 v = ((const float4*)src)[off];
    f16x4 o;
    o[0] = (f16)v.x; o[1] = (f16)v.y; o[2] = (f16)v.z; o[3] = (f16)v.w;
    *(f16x4*)(dst + (size_t)off * 4) = o;
}

// ---------------------------------------------------------------------------
// MFMA flash attention v3 (validated R10). Block = 4 waves = 4 GQA heads of
// one (b,hk,q0). S^T = mfma(a=K, b=Q); P feeds PV from registers.
// launch_bounds(256,2): (256,3) spilled (R9: 70 MB scratch writes).
// ---------------------------------------------------------------------------
#define VTS 200

__global__ __launch_bounds__(256, 2) void attn_mfma(const f16* __restrict__ qh,
                                                    const f16* __restrict__ khb,
                                                    const f16* __restrict__ vtb,
                                                    const float* __restrict__ sinks,
                                                    f16* __restrict__ oh) {
    __shared__ __align__(16) f16 Kl[192 * 64];
    __shared__ __align__(16) f16 Vt[64 * VTS];

    const int t  = threadIdx.x;
    const int q0 = blockIdx.x * 64;
    const int hk = blockIdx.y >> 1;
    const int hh = blockIdx.y & 1;
    const int b  = blockIdx.z;
    const int c0 = q0 - WINDOW;

    const int lane = t & 63;
    const int w    = t >> 6;
    const int lr   = lane & 15;
    const int quad = lane >> 4;
    const int srow = lane >> 3;
    const int gsw  = lane & 7;

    const f16* kg = khb + (size_t)(b * HK + hk) * Sv * HD;
    const f16* vg = vtb + (size_t)(b * HK + hk) * HD * Sv;

#pragma unroll
    for (int it = 0; it < 6; ++it) {
        const int row = (w * 6 + it) * 8 + srow;      // 0..191
        const int g   = gsw ^ (row & 7);
        int j = c0 + row;
        if (j < 0) j = 0;                             // garbage -> masked
        gload_lds16(kg + (size_t)j * HD + g * 8, Kl + (w * 6 + it) * 512);
    }
#pragma unroll
    for (int it = 0; it < 6; ++it) {
        const int i = it * 256 + t;                   // 0..1535
        const int d = i / 24, c = i % 24;
        int j0 = c0 + c * 8;
        if (j0 < 0) j0 = 0;                           // garbage -> masked
        const f16x8 val = *(const f16x8*)(vg + (size_t)d * Sv + j0);
        *(f16x8*)(&Vt[d * VTS + c * 8]) = val;
    }
    __syncthreads();

    const int h = hk * GQA + hh * 4 + w;

    f16x8 qf[4][2];
#pragma unroll
    for (int mt = 0; mt < 4; ++mt) {
        const f16* qrow = qh + (size_t)(b * Sv + q0 + mt * 16 + lr) * 4096 + h * 64;
#pragma unroll
        for (int ks = 0; ks < 2; ++ks)
            qf[mt][ks] = *(const f16x8*)(qrow + ks * 32 + quad * 8);
    }
    const float sk   = sinks[h];
    const int   smin = (c0 < 0) ? -c0 : 0;

    f32x4 O[4][4] = {};          // O^T tiles [mt][dt]: row d=quad*4+r, col q=lr
    float lsum[4] = {0.f, 0.f, 0.f, 0.f};

#pragma unroll
    for (int nt = 0; nt < 12; ++nt) {
        f16x8 kf[2];
#pragma unroll
        for (int ks = 0; ks < 2; ++ks)
            kf[ks] = *(const f16x8*)(&Kl[(nt * 16 + lr) * 64 + (((ks * 4 + quad) ^ (lr & 7)) * 8)]);
        f16x4 vf[4];
#pragma unroll
        for (int dt = 0; dt < 4; ++dt)
            vf[dt] = *(const f16x4*)(&Vt[(dt * 16 + lr) * VTS + nt * 16 + quad * 4]);

#pragma unroll
        for (int mt = 0; mt < 4; ++mt) {
            if (nt < mt || nt > mt + 8) continue;     // tile fully masked
            f32x4 S = {};
#pragma unroll
            for (int ks = 0; ks < 2; ++ks)
                S = __builtin_amdgcn_mfma_f32_16x16x32_f16(kf[ks], qf[mt][ks], S, 0, 0, 0);
            f16x4 pf;
#pragma unroll
            for (int r = 0; r < 4; ++r) {
                const int sl = nt * 16 + quad * 4 + r;
                const int mq = mt * 16 + lr;
                const bool ok = (sl > mq) && (sl <= mq + WINDOW) && (sl >= smin);
                const float p = ok ? __expf(S[r]) : 0.f;
                lsum[mt] += p;
                pf[r] = (f16)p;
            }
#pragma unroll
            for (int dt = 0; dt < 4; ++dt)
                O[mt][dt] = __builtin_amdgcn_mfma_f32_16x16x16f16(vf[dt], pf, O[mt][dt], 0, 0, 0);
        }
    }

    const float esk = __expf(sk);
#pragma unroll
    for (int mt = 0; mt < 4; ++mt) {
        float l = lsum[mt];
        l += __shfl_xor(l, 16, 64);
        l += __shfl_xor(l, 32, 64);
        lsum[mt] = 1.f / (l + esk);        // sink column joins denominator
    }

#pragma unroll
    for (int mt = 0; mt < 4; ++mt) {
        const float inv = lsum[mt];
        f16* orow = oh + (size_t)(b * Sv + q0 + mt * 16 + lr) * 4096 + h * 64;
#pragma unroll
        for (int dt = 0; dt < 4; ++dt) {
            f16x4 ov;
#pragma unroll
            for (int r = 0; r < 4; ++r) ov[r] = (f16)(O[mt][dt][r] * inv);
            *(f16x4*)(orow + dt * 16 + quad * 4) = ov;
        }
    }
}

// ---------------------------------------------------------------------------
extern "C" void kernel_launch(void* const* d_in, const int* in_sizes, int n_in,
                              void* d_out, int out_size, void* d_ws, size_t ws_size,
                              hipStream_t stream) {
    const float* x     = (const float*)d_in[0];
    const float* Wq    = (const float*)d_in[1];
    const float* bq    = (const float*)d_in[2];
    const float* Wk    = (const float*)d_in[3];
    const float* bk    = (const float*)d_in[4];
    const float* Wv    = (const float*)d_in[5];
    const float* bv    = (const float*)d_in[6];
    const float* Wo    = (const float*)d_in[7];
    const float* bo    = (const float*)d_in[8];
    const float* sinks = (const float*)d_in[9];
    float* out = (float*)d_out;

    f16* xh   = (f16*)d_ws;                    // 2,097,152
    f16* wqkv = xh + 2097152;                  // 5,242,880
    f16* qh   = wqkv + 5242880;                // 8,388,608
    f16* khb  = qh + 8388608;                  // 1,048,576  [B][HK][S][HD]
    f16* vtb  = khb + 1048576;                 // 1,048,576  [B][HK][HD][S]
    f16* woh  = vtb + 1048576;                 // 4,194,304  LIVE at o_gemm
    f16* oh   = woh + 4194304;                 // 8,388,608  LIVE at o_gemm
    float* bqkv = (float*)(oh + 8388608);      // 5120 fp32
    float* partials = (float*)d_ws;            // 32 MB, aliases dead prefix

    convert_all<<<dim3(C_WO / 256), dim3(256), 0, stream>>>(
        x, Wq, Wk, Wv, Wo, bq, bk, bv, xh, wqkv, woh, bqkv);

    qkv_gemm<<<dim3(512), dim3(256), 0, stream>>>(xh, wqkv, bqkv, qh, khb, vtb);

    attn_mfma<<<dim3(Sv / 64, HK * 2, Bv), dim3(256), 0, stream>>>(qh, khb, vtb, sinks, oh);

    o_gemm_split<<<dim3(512), dim3(256), 0, stream>>>(oh, woh, partials);
    reduce4<<<dim3(2048), dim3(256), 0, stream>>>(partials, bo, out);
}